// Round 4
// baseline (63.751 us; speedup 1.0000x reference)
//
#include <hip/hip_runtime.h>
#include <hip/hip_bf16.h>
#include <math.h>

typedef __attribute__((ext_vector_type(8))) short bf16x8;
typedef __attribute__((ext_vector_type(4))) float f32x4;
typedef unsigned short ushort_t;

#define NP 14400     // patches per video
#define KP 96        // padded feature dim (75 real + kn in slots 75/76)
#define NS 5         // column segments
#define SEG 2880     // cols per segment
#define NIT 45       // 64-col tiles per segment
#define TILEB 12288  // bytes per 64-col tile (64*96*2)

__device__ __forceinline__ ushort_t f2bf(float f) {
  unsigned u = __float_as_uint(f);
  u += 0x7FFF + ((u >> 16) & 1);   // RNE
  return (ushort_t)(u >> 16);
}
__device__ __forceinline__ float bf2f(ushort_t b) {
  return __uint_as_float(((unsigned)b) << 16);
}

// Fragment-order layouts (16B chunks laid out so consumer reads are
// base + lane*16 + imm — fully coalesced, conflict-free):
// K: chunk = ((p>>6)*12 + ((p>>4)&3)*3 + (d>>5))*64 + ((d>>3)&3)*16 + (p&15)
// Q: chunk = ((p>>4)*3 + (d>>5))*64 + ((d>>3)&3)*16 + (p&15)
__device__ __forceinline__ size_t kidx(int p, int d) {
  return ((size_t)(((p >> 6) * 12 + ((p >> 4) & 3) * 3 + (d >> 5)) * 64
          + ((d >> 3) & 3) * 16 + (p & 15))) * 8 + (d & 7);
}
__device__ __forceinline__ size_t qidx(int p, int d) {
  return ((size_t)(((p >> 4) * 3 + (d >> 5)) * 64
          + ((d >> 3) & 3) * 16 + (p & 15))) * 8 + (d & 7);
}

// ---------------- prep: patches -> bf16 in fragment order -----------------
// Q: slots 0..74 = bf16(-2*q), 75,76 = 1.0, rest 0; qn = fp32 norm.
// K: slots 0..74 = bf16(k), 75 = bf16(kn), 76 = bf16(kn residual), rest 0.
// Also inits rminb to ordered-uint +inf (0xFFFFFFFF).
__global__ __launch_bounds__(256) void prep_kernel(
    const float* __restrict__ resv, const float* __restrict__ valv,
    ushort_t* __restrict__ Qb, ushort_t* __restrict__ Kb,
    float* __restrict__ qn, unsigned* __restrict__ rminb) {
  int w = threadIdx.x >> 6;
  int lane = threadIdx.x & 63;
  int pg = blockIdx.x * 4 + w;          // 0..28799
  int isK = pg >= NP;
  int p = isK ? pg - NP : pg;
  const float* src = isK ? valv : resv;
  int t = p / 3600; int rem = p - t * 3600;
  int y = rem / 60;  int x = rem - y * 60;

  float v0, v1 = 0.f;
  {
    int d = lane;  // < 75 always
    int c = d / 25; int r = d - c * 25; int dy = r / 5; int dx = r - dy * 5;
    v0 = src[((c * 4 + t) * 64 + (y + dy)) * 64 + (x + dx)];
  }
  if (lane < 11) {
    int d = lane + 64;
    int c = d / 25; int r = d - c * 25; int dy = r / 5; int dx = r - dy * 5;
    v1 = src[((c * 4 + t) * 64 + (y + dy)) * 64 + (x + dx)];
  }
  ushort_t b0 = f2bf(v0), b1 = f2bf(v1);
  float f0 = bf2f(b0), f1 = bf2f(b1);

  float sq = f0 * f0 + f1 * f1;
  #pragma unroll
  for (int off = 1; off < 64; off <<= 1) sq += __shfl_xor(sq, off, 64);

  if (isK) {
    ushort_t khi = f2bf(sq);
    ushort_t klo = f2bf(sq - bf2f(khi));
    ushort_t s1 = (lane < 11) ? b1
                : (lane == 11 ? khi : (lane == 12 ? klo : (ushort_t)0));
    Kb[kidx(p, lane)] = b0;
    if (lane < 32) Kb[kidx(p, lane + 64)] = s1;
  } else {
    ushort_t s0 = f2bf(-2.f * f0);
    ushort_t s1 = (lane < 11) ? f2bf(-2.f * f1)
                : ((lane == 11 || lane == 12) ? (ushort_t)0x3F80 : (ushort_t)0);
    Qb[qidx(p, lane)] = s0;
    if (lane < 32) Qb[qidx(p, lane + 64)] = s1;
    if (lane == 0) { qn[p] = sq; rminb[p] = 0xFFFFFFFFu; }
  }
}

// ---------------- main: wave-private 96x16 tiles, barrier-free ------------
__global__ __launch_bounds__(256, 3) void knn_kernel(
    const ushort_t* __restrict__ Qb, const ushort_t* __restrict__ Kb,
    unsigned* __restrict__ rminb) {
  __shared__ char Bs[36864];   // 3 bufs x 4 waves x 3072 B, wave-private slots

  // XCD-bijective swizzle: 750 blocks, q=93 r=6; lin is ns-major.
  int b = blockIdx.x;
  int xcd = b & 7, pos = b >> 3;
  int lin = (xcd < 6 ? xcd * 94 : 564 + (xcd - 6) * 93) + pos;
  int ns = lin / 150, rowblk = lin - ns * 150;
  int brow = rowblk * 96;
  int lane = threadIdx.x & 63;
  int w = threadIdx.x >> 6;
  int l15 = lane & 15, l4 = lane >> 4;

  // global staging base: fragment-order Kb, lane-contiguous 1KB per issue
  const char* gW = (const char*)Kb + (size_t)(ns * 45) * TILEB
                   + w * 3072 + lane * 16;
  char* ldsW = &Bs[0] + w * 3072;

  auto stage = [&](int bi, int it) {
    const char* g = gW + (size_t)it * TILEB;
    #pragma unroll
    for (int ks = 0; ks < 3; ++ks)
      __builtin_amdgcn_global_load_lds(
          (const __attribute__((address_space(1))) void*)(g + ks * 1024),
          (__attribute__((address_space(3))) void*)(ldsW + bi * 12288 + ks * 1024),
          16, 0, 0);
  };

  // A fragments: 96 rows x 96 k, fragment-order Qb, lane-contiguous loads
  const char* Aw = (const char*)Qb + (size_t)(brow >> 4) * 3072 + lane * 16;
  bf16x8 af[6][3];
  #pragma unroll
  for (int rt = 0; rt < 6; ++rt)
    #pragma unroll
    for (int ks = 0; ks < 3; ++ks)
      af[rt][ks] = *(const bf16x8*)(Aw + (rt * 3 + ks) * 1024);

  float rmin[6][4];
  #pragma unroll
  for (int rt = 0; rt < 6; ++rt)
    #pragma unroll
    for (int j = 0; j < 4; ++j) rmin[rt][j] = INFINITY;

  const f32x4 fz = {0.f, 0.f, 0.f, 0.f};

  stage(0, 0);
  stage(1, 1);

  auto compute = [&](int bi) {
    const char* bb = &Bs[0] + w * 3072 + bi * 12288 + lane * 16;
    f32x4 acc[6];
    {
      bf16x8 bv = *(const bf16x8*)(bb);
      #pragma unroll
      for (int rt = 0; rt < 6; ++rt)
        acc[rt] = __builtin_amdgcn_mfma_f32_16x16x32_bf16(af[rt][0], bv, fz, 0, 0, 0);
    }
    #pragma unroll
    for (int ks = 1; ks < 3; ++ks) {
      bf16x8 bv = *(const bf16x8*)(bb + ks * 1024);
      #pragma unroll
      for (int rt = 0; rt < 6; ++rt)
        acc[rt] = __builtin_amdgcn_mfma_f32_16x16x32_bf16(af[rt][ks], bv, acc[rt], 0, 0, 0);
    }
    #pragma unroll
    for (int rt = 0; rt < 6; ++rt)
      #pragma unroll
      for (int j = 0; j < 4; ++j)
        rmin[rt][j] = fminf(rmin[rt][j], acc[rt][j]);
  };

  // main loop: 2-deep prefetch, counted vmcnt, NO barriers
  int bi = 0, nb = 2;
  for (int it = 0; it < NIT - 2; ++it) {
    stage(nb, it + 2);
    asm volatile("s_waitcnt vmcnt(6)" ::: "memory");
    __builtin_amdgcn_sched_barrier(0);
    compute(bi);
    bi = (bi == 2) ? 0 : bi + 1;
    nb = (nb == 2) ? 0 : nb + 1;
  }
  asm volatile("s_waitcnt vmcnt(3)" ::: "memory");
  __builtin_amdgcn_sched_barrier(0);
  compute(1);   // (NIT-2)%3 = 1
  asm volatile("s_waitcnt vmcnt(0)" ::: "memory");
  __builtin_amdgcn_sched_barrier(0);
  compute(2);   // (NIT-1)%3 = 2

  // min over the 16 key-cols (l15 lanes), then device atomicMin per row
  #pragma unroll
  for (int rt = 0; rt < 6; ++rt)
    #pragma unroll
    for (int j = 0; j < 4; ++j) {
      float m = rmin[rt][j];
      m = fminf(m, __shfl_xor(m, 1, 64));
      m = fminf(m, __shfl_xor(m, 2, 64));
      m = fminf(m, __shfl_xor(m, 4, 64));
      m = fminf(m, __shfl_xor(m, 8, 64));
      if (l15 == 0) {
        unsigned bu = __float_as_uint(m);
        unsigned tu = bu ^ (unsigned)(((int)bu >> 31) | (int)0x80000000);
        atomicMin(&rminb[brow + rt * 16 + l4 * 4 + j], tu);
      }
    }
}

// ---------------- final: untransform + add qn + deterministic sum ---------
__global__ __launch_bounds__(1024) void final_kernel(
    const unsigned* __restrict__ rminb, const float* __restrict__ qn,
    float* __restrict__ out) {
  int t = threadIdx.x;
  float s = 0.f;
  for (int i = t; i < NP; i += 1024) {
    unsigned u = rminb[i];
    unsigned bu = (u & 0x80000000u) ? (u ^ 0x80000000u) : ~u;
    s += __uint_as_float(bu) + qn[i];
  }
  #pragma unroll
  for (int off = 32; off; off >>= 1) s += __shfl_down(s, off, 64);
  __shared__ float red[16];
  if ((t & 63) == 0) red[t >> 6] = s;
  __syncthreads();
  if (t == 0) {
    float tot = 0.f;
    #pragma unroll
    for (int i2 = 0; i2 < 16; ++i2) tot += red[i2];
    out[0] = tot;
  }
}

extern "C" void kernel_launch(void* const* d_in, const int* in_sizes, int n_in,
                              void* d_out, int out_size, void* d_ws, size_t ws_size,
                              hipStream_t stream) {
  const float* resv = (const float*)d_in[0];
  const float* valv = (const float*)d_in[1];
  char* ws = (char*)d_ws;
  ushort_t* Qb    = (ushort_t*)ws;                 // 2,764,800 B
  ushort_t* Kb    = (ushort_t*)(ws + 2764800);     // 2,764,800 B
  float* qn       = (float*)(ws + 5529600);        //    57,600 B
  unsigned* rminb = (unsigned*)(ws + 5587200);     //    57,600 B
  float* out = (float*)d_out;

  prep_kernel<<<7200, 256, 0, stream>>>(resv, valv, Qb, Kb, qn, rminb);
  knn_kernel<<<750, 256, 0, stream>>>(Qb, Kb, rminb);
  final_kernel<<<1, 1024, 0, stream>>>(rminb, qn, out);
}